// Round 9
// baseline (1639.029 us; speedup 1.0000x reference)
//
#include <hip/hip_runtime.h>
#include <math.h>

// ATTRIBUTION ROUND #2: byte-exact R8 kernels, but k2 (energies) launched 17x
// (idempotent: rewrites identical energies into d_out before the single k3).
// T_k2 = (dur_us - 112.0)/16. Recover best-known by dropping the loop.

// Problem constants (from setup_inputs): H=1024, B=32, S=4096, all f32.
constexpr int H = 1024;
constexpr int B = 32;
constexpr int S = 4096;

// ---------------------------------------------------------------------------
// Kernel 1 v3 (unchanged from R6/R7/R8): v[b,h] = sum_g hidden[b,g] * W[g,h]
// ---------------------------------------------------------------------------
__global__ __launch_bounds__(256) void compute_v_kernel(
    const float* __restrict__ hidden, const float* __restrict__ W,
    float* __restrict__ v)
{
    const int b  = blockIdx.x >> 4;
    const int hc = blockIdx.x & 15;           // 64-wide h chunk
    const int hq = threadIdx.x & 15;          // h-quad within chunk
    const int gg = threadIdx.x >> 4;          // 16-way g-split
    const int hquad = hc * 16 + hq;           // global h/4 index
    const float* __restrict__ hb = hidden + b * H;
    const float4* __restrict__ W4 = (const float4*)W;   // W4[g*256 + h/4]

    float4 aE = {0,0,0,0}, aO = {0,0,0,0};
    const int g0 = gg * 64;
    #pragma unroll 4
    for (int g = g0; g < g0 + 64; g += 2) {
        float  h0 = hb[g], h1 = hb[g + 1];
        float4 w0 = W4[(size_t)(g + 0) * 256 + hquad];
        float4 w1 = W4[(size_t)(g + 1) * 256 + hquad];
        aE.x = fmaf(h0, w0.x, aE.x); aE.y = fmaf(h0, w0.y, aE.y);
        aE.z = fmaf(h0, w0.z, aE.z); aE.w = fmaf(h0, w0.w, aE.w);
        aO.x = fmaf(h1, w1.x, aO.x); aO.y = fmaf(h1, w1.y, aO.y);
        aO.z = fmaf(h1, w1.z, aO.z); aO.w = fmaf(h1, w1.w, aO.w);
    }
    float4 acc = {aE.x + aO.x, aE.y + aO.y, aE.z + aO.z, aE.w + aO.w};

    __shared__ float4 part[16][16];
    part[gg][hq] = acc;
    __syncthreads();
    if (threadIdx.x < 64) {                   // stage 1: 16 -> 4 partials
        const int q  = threadIdx.x & 15;
        const int kk = threadIdx.x >> 4;
        float4 s = part[kk * 4 + 0][q];
        #pragma unroll
        for (int j = 1; j < 4; ++j) {
            float4 p = part[kk * 4 + j][q];
            s.x += p.x; s.y += p.y; s.z += p.z; s.w += p.w;
        }
        part[kk * 4][q] = s;
    }
    __syncthreads();
    if (threadIdx.x < 16) {                   // stage 2: 4 -> 1, store
        const int q = threadIdx.x;
        float4 s = part[0][q];
        #pragma unroll
        for (int j = 1; j < 4; ++j) {
            float4 p = part[j * 4][q];
            s.x += p.x; s.y += p.y; s.z += p.z; s.w += p.w;
        }
        ((float4*)(v + b * H))[hquad] = s;
    }
}

// ---------------------------------------------------------------------------
// Kernel 2 v5 (unchanged from R8): contiguous sweep + 1-deep prefetch.
// ---------------------------------------------------------------------------
#define LOAD8(pfx, pA, pB)                                                   \
    pfx##a0 = (pA)[lane];        pfx##a1 = (pA)[64 + lane];                  \
    pfx##a2 = (pA)[128 + lane];  pfx##a3 = (pA)[192 + lane];                 \
    pfx##b0 = (pB)[lane];        pfx##b1 = (pB)[64 + lane];                  \
    pfx##b2 = (pB)[128 + lane];  pfx##b3 = (pB)[192 + lane];

#define COMPUTE_STORE(pfx, kk)                                               \
    {                                                                        \
        float pa0 = pfx##a0.x * wa0.x, pa1 = pfx##a1.x * wa1.x;              \
        float pb0 = pfx##b0.x * wb0.x, pb1 = pfx##b1.x * wb1.x;              \
        pa0 = fmaf(pfx##a0.y, wa0.y, pa0); pa1 = fmaf(pfx##a1.y, wa1.y, pa1);\
        pb0 = fmaf(pfx##b0.y, wb0.y, pb0); pb1 = fmaf(pfx##b1.y, wb1.y, pb1);\
        pa0 = fmaf(pfx##a0.z, wa0.z, pa0); pa1 = fmaf(pfx##a1.z, wa1.z, pa1);\
        pb0 = fmaf(pfx##b0.z, wb0.z, pb0); pb1 = fmaf(pfx##b1.z, wb1.z, pb1);\
        pa0 = fmaf(pfx##a0.w, wa0.w, pa0); pa1 = fmaf(pfx##a1.w, wa1.w, pa1);\
        pb0 = fmaf(pfx##b0.w, wb0.w, pb0); pb1 = fmaf(pfx##b1.w, wb1.w, pb1);\
        pa0 = fmaf(pfx##a2.x, wa2.x, pa0); pa1 = fmaf(pfx##a3.x, wa3.x, pa1);\
        pb0 = fmaf(pfx##b2.x, wb2.x, pb0); pb1 = fmaf(pfx##b3.x, wb3.x, pb1);\
        pa0 = fmaf(pfx##a2.y, wa2.y, pa0); pa1 = fmaf(pfx##a3.y, wa3.y, pa1);\
        pb0 = fmaf(pfx##b2.y, wb2.y, pb0); pb1 = fmaf(pfx##b3.y, wb3.y, pb1);\
        pa0 = fmaf(pfx##a2.z, wa2.z, pa0); pa1 = fmaf(pfx##a3.z, wa3.z, pa1);\
        pb0 = fmaf(pfx##b2.z, wb2.z, pb0); pb1 = fmaf(pfx##b3.z, wb3.z, pb1);\
        pa0 = fmaf(pfx##a2.w, wa2.w, pa0); pa1 = fmaf(pfx##a3.w, wa3.w, pa1);\
        pb0 = fmaf(pfx##b2.w, wb2.w, pb0); pb1 = fmaf(pfx##b3.w, wb3.w, pb1);\
        float pa = pa0 + pa1;                                                \
        float pb = pb0 + pb1;                                                \
        _Pragma("unroll")                                                    \
        for (int off = 32; off > 0; off >>= 1) {                             \
            pa += __shfl_xor(pa, off, 64);                                   \
            pb += __shfl_xor(pb, off, 64);                                   \
        }                                                                    \
        if (lane == 0) {                                                     \
            energies[(size_t)b0 * S + s_base + (kk)] = pa;                   \
            energies[(size_t)b1 * S + s_base + (kk)] = pb;                   \
        }                                                                    \
    }

__global__ __launch_bounds__(1024) void energies_kernel(
    const float* __restrict__ enc, const float* __restrict__ v,
    float* __restrict__ energies)
{
    const int w    = threadIdx.x >> 6;        // wave 0..15
    const int lane = threadIdx.x & 63;
    const int b0 = w, b1 = w + 16;
    const size_t base   = (size_t)blockIdx.x * 512;   // first row of block
    const int    s_base = blockIdx.x * 16;

    const float4* __restrict__ v4 = (const float4*)v;
    const float4 wa0 = v4[b0 * 256 + lane],       wa1 = v4[b0 * 256 + 64 + lane],
                 wa2 = v4[b0 * 256 + 128 + lane], wa3 = v4[b0 * 256 + 192 + lane];
    const float4 wb0 = v4[b1 * 256 + lane],       wb1 = v4[b1 * 256 + 64 + lane],
                 wb2 = v4[b1 * 256 + 128 + lane], wb3 = v4[b1 * 256 + 192 + lane];

    const float4* __restrict__ rbase = (const float4*)enc + (base + (size_t)w) * 256;

    float4 xa0, xa1, xa2, xa3, xb0, xb1, xb2, xb3;   // current
    float4 ya0, ya1, ya2, ya3, yb0, yb1, yb2, yb3;   // next

    { const float4* pA = rbase; const float4* pB = rbase + 4096;
      LOAD8(x, pA, pB) }

    #pragma unroll
    for (int k = 0; k < 16; k += 2) {
        { const float4* pA = rbase + (size_t)(k + 1) * 8192;
          const float4* pB = pA + 4096;
          LOAD8(y, pA, pB) }
        COMPUTE_STORE(x, k)
        if (k + 2 < 16) {
            const float4* pA = rbase + (size_t)(k + 2) * 8192;
            const float4* pB = pA + 4096;
            LOAD8(x, pA, pB)
        }
        COMPUTE_STORE(y, k + 1)
    }
}

// ---------------------------------------------------------------------------
// Kernel 3 v2 (unchanged from R8): 32 blocks x 1024 thr, one float4/thread.
// ---------------------------------------------------------------------------
__global__ __launch_bounds__(1024) void softmax_kernel(float* __restrict__ out)
{
    const int b = blockIdx.x;
    float4* __restrict__ row4 = (float4*)(out + (size_t)b * S);  // 1024 float4
    const int w = threadIdx.x >> 6;
    const int lane = threadIdx.x & 63;
    __shared__ float redm[16];
    __shared__ float reds[16];

    float4 x = row4[threadIdx.x];
    float m = fmaxf(fmaxf(x.x, x.y), fmaxf(x.z, x.w));
    #pragma unroll
    for (int off = 32; off > 0; off >>= 1)
        m = fmaxf(m, __shfl_xor(m, off, 64));
    if (lane == 0) redm[w] = m;
    __syncthreads();
    float M = redm[0];
    #pragma unroll
    for (int i = 1; i < 16; ++i) M = fmaxf(M, redm[i]);

    float4 e;
    e.x = __expf(x.x - M); e.y = __expf(x.y - M);
    e.z = __expf(x.z - M); e.w = __expf(x.w - M);
    float s = (e.x + e.y) + (e.z + e.w);
    #pragma unroll
    for (int off = 32; off > 0; off >>= 1)
        s += __shfl_xor(s, off, 64);
    if (lane == 0) reds[w] = s;
    __syncthreads();
    float T = reds[0];
    #pragma unroll
    for (int i = 1; i < 16; ++i) T += reds[i];
    const float inv = 1.0f / T;
    e.x *= inv; e.y *= inv; e.z *= inv; e.w *= inv;
    row4[threadIdx.x] = e;
}

extern "C" void kernel_launch(void* const* d_in, const int* in_sizes, int n_in,
                              void* d_out, int out_size, void* d_ws, size_t ws_size,
                              hipStream_t stream) {
    const float* hidden = (const float*)d_in[0];   // [1, B, H]
    const float* enc    = (const float*)d_in[1];   // [S, B, H]
    const float* W      = (const float*)d_in[2];   // [H, H]
    // d_in[3] = attn_b: per-b constant in energies -> cancels under softmax.
    float* out = (float*)d_out;                    // [B, 1, S]
    float* v   = (float*)d_ws;                     // B*H floats

    compute_v_kernel<<<dim3(B * 16), dim3(256), 0, stream>>>(hidden, W, v);
    // 17x launch: idempotent; T_k2 = (dur_us - 112.0)/16
    for (int rep = 0; rep < 17; ++rep)
        energies_kernel<<<dim3(256), dim3(1024), 0, stream>>>(enc, v, out);
    softmax_kernel<<<dim3(B), dim3(1024), 0, stream>>>(out);
}

// Round 10
// 106.888 us; speedup vs baseline: 15.3340x; 15.3340x over previous
//
#include <hip/hip_runtime.h>
#include <math.h>

// Problem constants (from setup_inputs): H=1024, B=32, S=4096, all f32.
constexpr int H = 1024;
constexpr int B = 32;
constexpr int S = 4096;

typedef float f4 __attribute__((ext_vector_type(4)));   // native clang vector
#define NTL(p) __builtin_nontemporal_load(p)

// ---------------------------------------------------------------------------
// Kernel 1 v4: W-READ-ONCE. Grid 256 blocks; block = 4 h-columns x all 32 b.
// R9 attribution showed v3 ~8-10us: its 32x b-redundant W reads = 128 MiB of
// cold L2/L3 traffic per replay. v4 reads each W element once chip-wide
// (4 MiB): per g, float4 W[g][h0..h0+4) is identical across lanes (broadcast).
// hidden[32][1024] staged in 128 KiB dynamic LDS with XOR swizzle (g^b) so
// the 32 b-lanes hit 32 distinct banks (unswizzled = 32-way conflict).
// Threads: tid = gs*32 + b; gs = 8-way g-split (128 g each).
// ---------------------------------------------------------------------------
__global__ __launch_bounds__(256) void compute_v_kernel(
    const float* __restrict__ hidden, const float* __restrict__ W,
    float* __restrict__ v)
{
    extern __shared__ float smem[];           // 32*1024 floats = 128 KiB
    const int tid = threadIdx.x;
    const int b   = tid & 31;
    const int gs  = tid >> 5;                 // 0..7
    const int hq  = blockIdx.x;               // h-quad index; h0 = hq*4

    // stage hidden -> LDS, XOR-swizzled rows (coalesced global reads)
    for (int i = tid; i < B * H; i += 256) {
        const int bb = i >> 10, g = i & 1023;
        smem[(bb << 10) | (g ^ bb)] = hidden[i];   // bb<32 -> g^bb stays in row
    }
    __syncthreads();

    const f4* __restrict__ Wq = (const f4*)W;      // Wq[g*256 + hq]
    const float* __restrict__ hrow = smem + (b << 10);
    f4 acc = {0.f, 0.f, 0.f, 0.f};
    const int g0 = gs * 128;
    #pragma unroll 4
    for (int j = 0; j < 128; ++j) {
        const int g = g0 + j;
        const float hv = hrow[g ^ b];              // bank-conflict-free
        const f4 wv = Wq[(size_t)g * 256 + hq];    // lane-broadcast
        acc.x = fmaf(hv, wv.x, acc.x);
        acc.y = fmaf(hv, wv.y, acc.y);
        acc.z = fmaf(hv, wv.z, acc.z);
        acc.w = fmaf(hv, wv.w, acc.w);
    }
    __syncthreads();                          // hidden reads done; reuse smem
    f4* part = (f4*)smem;                     // part[gs*32 + b], 4 KiB
    part[(gs << 5) | b] = acc;
    __syncthreads();
    if (tid < 32) {                           // tid == b
        f4 s = part[tid];
        #pragma unroll
        for (int k = 1; k < 8; ++k) {
            const f4 p = part[(k << 5) | tid];
            s.x += p.x; s.y += p.y; s.z += p.z; s.w += p.w;
        }
        ((f4*)v)[tid * 256 + hq] = s;         // v[b][h0..h0+3]
    }
}

// ---------------------------------------------------------------------------
// Kernel 2 v6: contiguous sweep + 1-deep prefetch (R8 skeleton), with
//  (a) ADJACENT row pairs per wave: b0=2w, b1=2w+1 -> each wave-iter reads
//      8 KiB contiguous (was two rows 64 KiB apart),
//  (b) nontemporal enc loads (single-use stream; skip cache allocation).
// ---------------------------------------------------------------------------
#define LOAD8(pfx, pA, pB)                                                   \
    pfx##a0 = NTL((pA) + lane);        pfx##a1 = NTL((pA) + 64 + lane);      \
    pfx##a2 = NTL((pA) + 128 + lane);  pfx##a3 = NTL((pA) + 192 + lane);     \
    pfx##b0 = NTL((pB) + lane);        pfx##b1 = NTL((pB) + 64 + lane);      \
    pfx##b2 = NTL((pB) + 128 + lane);  pfx##b3 = NTL((pB) + 192 + lane);

#define COMPUTE_STORE(pfx, kk)                                               \
    {                                                                        \
        float pa0 = pfx##a0.x * wa0.x, pa1 = pfx##a1.x * wa1.x;              \
        float pb0 = pfx##b0.x * wb0.x, pb1 = pfx##b1.x * wb1.x;              \
        pa0 = fmaf(pfx##a0.y, wa0.y, pa0); pa1 = fmaf(pfx##a1.y, wa1.y, pa1);\
        pb0 = fmaf(pfx##b0.y, wb0.y, pb0); pb1 = fmaf(pfx##b1.y, wb1.y, pb1);\
        pa0 = fmaf(pfx##a0.z, wa0.z, pa0); pa1 = fmaf(pfx##a1.z, wa1.z, pa1);\
        pb0 = fmaf(pfx##b0.z, wb0.z, pb0); pb1 = fmaf(pfx##b1.z, wb1.z, pb1);\
        pa0 = fmaf(pfx##a0.w, wa0.w, pa0); pa1 = fmaf(pfx##a1.w, wa1.w, pa1);\
        pb0 = fmaf(pfx##b0.w, wb0.w, pb0); pb1 = fmaf(pfx##b1.w, wb1.w, pb1);\
        pa0 = fmaf(pfx##a2.x, wa2.x, pa0); pa1 = fmaf(pfx##a3.x, wa3.x, pa1);\
        pb0 = fmaf(pfx##b2.x, wb2.x, pb0); pb1 = fmaf(pfx##b3.x, wb3.x, pb1);\
        pa0 = fmaf(pfx##a2.y, wa2.y, pa0); pa1 = fmaf(pfx##a3.y, wa3.y, pa1);\
        pb0 = fmaf(pfx##b2.y, wb2.y, pb0); pb1 = fmaf(pfx##b3.y, wb3.y, pb1);\
        pa0 = fmaf(pfx##a2.z, wa2.z, pa0); pa1 = fmaf(pfx##a3.z, wa3.z, pa1);\
        pb0 = fmaf(pfx##b2.z, wb2.z, pb0); pb1 = fmaf(pfx##b3.z, wb3.z, pb1);\
        pa0 = fmaf(pfx##a2.w, wa2.w, pa0); pa1 = fmaf(pfx##a3.w, wa3.w, pa1);\
        pb0 = fmaf(pfx##b2.w, wb2.w, pb0); pb1 = fmaf(pfx##b3.w, wb3.w, pb1);\
        float pa = pa0 + pa1;                                                \
        float pb = pb0 + pb1;                                                \
        _Pragma("unroll")                                                    \
        for (int off = 32; off > 0; off >>= 1) {                             \
            pa += __shfl_xor(pa, off, 64);                                   \
            pb += __shfl_xor(pb, off, 64);                                   \
        }                                                                    \
        if (lane == 0) {                                                     \
            energies[(size_t)b0 * S + s_base + (kk)] = pa;                   \
            energies[(size_t)b1 * S + s_base + (kk)] = pb;                   \
        }                                                                    \
    }

__global__ __launch_bounds__(1024) void energies_kernel(
    const float* __restrict__ enc, const float* __restrict__ v,
    float* __restrict__ energies)
{
    const int w    = threadIdx.x >> 6;        // wave 0..15
    const int lane = threadIdx.x & 63;
    const int b0 = 2 * w, b1 = 2 * w + 1;     // adjacent rows (8 KiB contig)
    const size_t base   = (size_t)blockIdx.x * 512;   // first row of block
    const int    s_base = blockIdx.x * 16;

    const f4* __restrict__ v4 = (const f4*)v;
    const f4 wa0 = v4[b0 * 256 + lane],       wa1 = v4[b0 * 256 + 64 + lane],
             wa2 = v4[b0 * 256 + 128 + lane], wa3 = v4[b0 * 256 + 192 + lane];
    const f4 wb0 = v4[b1 * 256 + lane],       wb1 = v4[b1 * 256 + 64 + lane],
             wb2 = v4[b1 * 256 + 128 + lane], wb3 = v4[b1 * 256 + 192 + lane];

    // rowA(k) = (base + 2w + 32k) * 256 f4;  rowB(k) = rowA(k) + 256 (next row)
    const f4* __restrict__ rbase = (const f4*)enc + (base + 2u * w) * 256;

    f4 xa0, xa1, xa2, xa3, xb0, xb1, xb2, xb3;   // current
    f4 ya0, ya1, ya2, ya3, yb0, yb1, yb2, yb3;   // next

    { const f4* pA = rbase; const f4* pB = rbase + 256;
      LOAD8(x, pA, pB) }

    #pragma unroll
    for (int k = 0; k < 16; k += 2) {
        { const f4* pA = rbase + (size_t)(k + 1) * 8192;
          const f4* pB = pA + 256;
          LOAD8(y, pA, pB) }
        COMPUTE_STORE(x, k)
        if (k + 2 < 16) {
            const f4* pA = rbase + (size_t)(k + 2) * 8192;
            const f4* pB = pA + 256;
            LOAD8(x, pA, pB)
        }
        COMPUTE_STORE(y, k + 1)
    }
}

// ---------------------------------------------------------------------------
// Kernel 3 v2 (unchanged from R8): 32 blocks x 1024 thr, one float4/thread.
// ---------------------------------------------------------------------------
__global__ __launch_bounds__(1024) void softmax_kernel(float* __restrict__ out)
{
    const int b = blockIdx.x;
    float4* __restrict__ row4 = (float4*)(out + (size_t)b * S);  // 1024 float4
    const int w = threadIdx.x >> 6;
    const int lane = threadIdx.x & 63;
    __shared__ float redm[16];
    __shared__ float reds[16];

    float4 x = row4[threadIdx.x];
    float m = fmaxf(fmaxf(x.x, x.y), fmaxf(x.z, x.w));
    #pragma unroll
    for (int off = 32; off > 0; off >>= 1)
        m = fmaxf(m, __shfl_xor(m, off, 64));
    if (lane == 0) redm[w] = m;
    __syncthreads();
    float M = redm[0];
    #pragma unroll
    for (int i = 1; i < 16; ++i) M = fmaxf(M, redm[i]);

    float4 e;
    e.x = __expf(x.x - M); e.y = __expf(x.y - M);
    e.z = __expf(x.z - M); e.w = __expf(x.w - M);
    float s = (e.x + e.y) + (e.z + e.w);
    #pragma unroll
    for (int off = 32; off > 0; off >>= 1)
        s += __shfl_xor(s, off, 64);
    if (lane == 0) reds[w] = s;
    __syncthreads();
    float T = reds[0];
    #pragma unroll
    for (int i = 1; i < 16; ++i) T += reds[i];
    const float inv = 1.0f / T;
    e.x *= inv; e.y *= inv; e.z *= inv; e.w *= inv;
    row4[threadIdx.x] = e;
}

extern "C" void kernel_launch(void* const* d_in, const int* in_sizes, int n_in,
                              void* d_out, int out_size, void* d_ws, size_t ws_size,
                              hipStream_t stream) {
    const float* hidden = (const float*)d_in[0];   // [1, B, H]
    const float* enc    = (const float*)d_in[1];   // [S, B, H]
    const float* W      = (const float*)d_in[2];   // [H, H]
    // d_in[3] = attn_b: per-b constant in energies -> cancels under softmax.
    float* out = (float*)d_out;                    // [B, 1, S]
    float* v   = (float*)d_ws;                     // B*H floats

    compute_v_kernel<<<dim3(256), dim3(256), 32 * 1024 * 4, stream>>>(hidden, W, v);
    energies_kernel<<<dim3(256), dim3(1024), 0, stream>>>(enc, v, out);
    softmax_kernel<<<dim3(B), dim3(1024), 0, stream>>>(out);
}